// Round 7
// baseline (128.435 us; speedup 1.0000x reference)
//
#include <hip/hip_runtime.h>
#include <hip/hip_bf16.h>

// VITS length-regulator: attn is one-hot in t per output frame y, so the
// einsums are gathers. Two kernels:
//  1) k_scan_tmap: per-batch ceil(exp(logw))*mask -> shuffle-based scan
//     (2 barriers) -> y_len; binary search per y from LDS cum -> tmap+y_mask.
//  2) k_expand1: ONE channel per block, 256 threads (3072 blocks -> 8
//     resident blocks/CU = 32 waves/CU, grid no longer caps occupancy).
//     Stage 1 row of m + exp(logs) in LDS; noise/tmap loads issued BEFORE
//     the barrier so their latency hides under staging.
//
// History: R1 direct-gather 50us (latency-bound, 21% HBM). R3 LDS+vec4
// -> ~26us. R4 CPB=2 + up-front loads -> 127.9 total. R5 CPB=4 regressed
// (12 waves/CU). R6 = R4 config + shuffle-scan: 127.4.
// Shapes fixed by the problem: B=16, C=192, TX=1024, MAX_Y=4096.

__global__ void __launch_bounds__(1024) k_scan_tmap(
        const float* __restrict__ logw,
        const int* __restrict__ x_lengths,
        int* __restrict__ tmap,
        float* __restrict__ y_mask,
        int tx, int max_y) {
    const int b    = blockIdx.x;
    const int t    = threadIdx.x;       // blockDim.x == tx == 1024
    const int lane = t & 63;
    const int wid  = t >> 6;            // 16 waves
    __shared__ float s[1024];
    __shared__ float wsum[16];
    __shared__ int yl_sh;

    int xl = x_lengths[b];
    if (xl < 1) xl = 1;

    float w = (t < xl) ? ceilf(expf(logw[b * tx + t])) : 0.f;

    // Wave-level inclusive scan (values are integer-valued floats < 2^24:
    // exact in any association order -> bit-matches jnp.cumsum).
    float v = w;
#pragma unroll
    for (int off = 1; off < 64; off <<= 1) {
        float u = __shfl_up(v, off, 64);
        if (lane >= off) v += u;
    }
    if (lane == 63) wsum[wid] = v;
    __syncthreads();

    // Wave 0 scans the 16 wave totals in-register.
    if (wid == 0) {
        float sv = (lane < 16) ? wsum[lane] : 0.f;
#pragma unroll
        for (int off = 1; off < 16; off <<= 1) {
            float u = __shfl_up(sv, off, 64);
            if (lane >= off) sv += u;
        }
        if (lane < 16) wsum[lane] = sv;   // inclusive scan of wave sums
    }
    __syncthreads();

    float cum = v + ((wid > 0) ? wsum[wid - 1] : 0.f);
    s[t] = cum;
    if (t == tx - 1)
        yl_sh = (int)fminf(fmaxf(cum, 1.f), (float)max_y);
    __syncthreads();
    const int yl = yl_sh;

    // Each thread handles 4 consecutive y: binary search in LDS cum.
    const int y0 = t * 4;               // max_y/4 == 1024 == blockDim
    int res[4];
    float msk[4];
#pragma unroll
    for (int k = 0; k < 4; ++k) {
        const int y = y0 + k;
        int r = -1;
        if (y < yl) {
            float fy = (float)y;
            int lo = 0, hi = tx - 1;
            while (lo < hi) {
                int mid = (lo + hi) >> 1;
                if (s[mid] > fy) hi = mid; else lo = mid + 1;
            }
            r = lo;
        }
        res[k] = r;
        msk[k] = (y < yl) ? 1.f : 0.f;
    }
    ((int4*)(tmap + (size_t)b * max_y))[t] =
        make_int4(res[0], res[1], res[2], res[3]);
    ((float4*)(y_mask + (size_t)b * max_y))[t] =
        make_float4(msk[0], msk[1], msk[2], msk[3]);
}

// 1 channel per block, 256 threads, 4 y-vec iterations.
// All global loads issued up-front; noise/tmap before the barrier.
__global__ void __launch_bounds__(256) k_expand1(
        const float* __restrict__ m_p,
        const float* __restrict__ logs_p,
        const float* __restrict__ noise,
        const int* __restrict__ tmap,
        float* __restrict__ z,
        int C, int tx, int max_y) {
    __shared__ float sm[1024];   // m_p row       (4 KB)
    __shared__ float se[1024];   // exp(logs) row (4 KB)

    const int tid = threadIdx.x;
    const int bc  = blockIdx.x;             // b*C + c
    const int b   = bc / C;

    // Stage loads (needed first).
    float4 mv = ((const float4*)(m_p    + (size_t)bc * tx))[tid];
    float4 lv = ((const float4*)(logs_p + (size_t)bc * tx))[tid];

    // Independent loads issued now; latency hides under stage+barrier.
    const int4*   t4 = (const int4*)  (tmap  + (size_t)b  * max_y);
    const float4* n4 = (const float4*)(noise + (size_t)bc * max_y);
    int4   tv[4];
    float4 nv[4];
#pragma unroll
    for (int it = 0; it < 4; ++it)
        tv[it] = t4[tid + it * 256];
#pragma unroll
    for (int it = 0; it < 4; ++it)
        nv[it] = n4[tid + it * 256];

    int j = tid * 4;
    sm[j + 0] = mv.x; sm[j + 1] = mv.y; sm[j + 2] = mv.z; sm[j + 3] = mv.w;
    se[j + 0] = expf(lv.x); se[j + 1] = expf(lv.y);
    se[j + 2] = expf(lv.z); se[j + 3] = expf(lv.w);
    __syncthreads();

    float4* z4 = (float4*)(z + (size_t)bc * max_y);
#pragma unroll
    for (int it = 0; it < 4; ++it) {
        const int4   t = tv[it];
        const float4 n = nv[it];
        float4 o;
        o.x = (t.x >= 0) ? fmaf(n.x, se[t.x], sm[t.x]) : n.x;
        o.y = (t.y >= 0) ? fmaf(n.y, se[t.y], sm[t.y]) : n.y;
        o.z = (t.z >= 0) ? fmaf(n.z, se[t.z], sm[t.z]) : n.z;
        o.w = (t.w >= 0) ? fmaf(n.w, se[t.w], sm[t.w]) : n.w;
        z4[tid + it * 256] = o;
    }
}

extern "C" void kernel_launch(void* const* d_in, const int* in_sizes, int n_in,
                              void* d_out, int out_size, void* d_ws, size_t ws_size,
                              hipStream_t stream) {
    const float* m_p    = (const float*)d_in[0];
    const float* logs_p = (const float*)d_in[1];
    const float* logw   = (const float*)d_in[2];
    const float* noise  = (const float*)d_in[3];
    const int*   x_len  = (const int*)  d_in[4];

    const int B    = in_sizes[4];                 // 16
    const int TX   = in_sizes[2] / B;             // 1024
    const int C    = in_sizes[0] / (B * TX);      // 192
    const int MAXY = in_sizes[3] / (B * C);       // 4096

    float* z      = (float*)d_out;                        // [B, C, MAXY]
    float* y_mask = (float*)d_out + (size_t)B * C * MAXY; // [B, 1, MAXY]

    int* tmap = (int*)d_ws;                       // B*MAXY ints

    k_scan_tmap<<<dim3(B), dim3(1024), 0, stream>>>(
        logw, x_len, tmap, y_mask, TX, MAXY);

    k_expand1<<<dim3(B * C), dim3(256), 0, stream>>>(
        m_p, logs_p, noise, tmap, z, C, TX, MAXY);
}